// Round 10
// baseline (192.675 us; speedup 1.0000x reference)
//
#include <hip/hip_runtime.h>
#include <hip/hip_bf16.h>

#define B_    4
#define C_    64
#define H_    192
#define W_    192
#define TAPS_ 9
#define MID_  12
#define HW_   (H_ * W_)
#define K_TOT 576                      // C_ * TAPS_
#define AT_STRIDE 72                   // bf16 elems per aT/Bbuf row (8 chunks + pad)

constexpr float STD_ = 0.47140452079103173f;  // sqrt(2)/3

using bf16 = __hip_bfloat16;
typedef __attribute__((ext_vector_type(4)))  float f32x4;
typedef __attribute__((ext_vector_type(16))) float f32x16;
typedef __attribute__((ext_vector_type(8)))  short short8;

__device__ __forceinline__ unsigned short f2bf_bits(float v) {
    union { bf16 h; unsigned short u; } cv;
    cv.h = __float2bfloat16(v);   // RNE
    return cv.u;
}

// XOR swizzle: 16-B chunks within a row permuted by key=(storage_row>>2)&7.
__device__ __forceinline__ int at_word(int row, int cw) {
    int key = (row >> 2) & 7;
    return row * (AT_STRIDE / 2) + ((((cw >> 2) ^ key) & 7) << 2) + (cw & 3);
}

// ---------------------------------------------------------------------------
// k_pre: {w2 repack -> bf16 [o][t*64+c]} (blocks 0..143) and
//        {x row partial sums} (blocks 144..911).
// ---------------------------------------------------------------------------
__global__ __launch_bounds__(256) void k_pre(const float* __restrict__ x,
                                             const float* __restrict__ w2,
                                             unsigned short* __restrict__ w2bf,
                                             float* __restrict__ partials) {
    int bx = blockIdx.x;
    if (bx < 144) {
        int s = bx * 256 + threadIdx.x;
        int o = s / K_TOT;
        int rem = s - o * K_TOT;
        int c = rem / TAPS_;
        int t = rem - c * TAPS_;
        w2bf[o * K_TOT + t * 64 + c] = f2bf_bits(w2[s]);
        return;
    }
    bx -= 144;
    int bc = bx / 3, part = bx - 3 * (bx / 3);
    const float4* p = (const float4*)(x + (size_t)bc * HW_ + part * 12288);
    float s = 0.f;
    #pragma unroll
    for (int k = 0; k < 12; ++k) {
        float4 u = p[threadIdx.x + k * 256];
        s += u.x + u.y + u.z + u.w;
    }
    #pragma unroll
    for (int off = 32; off; off >>= 1) s += __shfl_down(s, off);
    __shared__ float red[4];
    if ((threadIdx.x & 63) == 0) red[threadIdx.x >> 6] = s;
    __syncthreads();
    if (threadIdx.x == 0)
        partials[bx] = red[0] + red[1] + red[2] + red[3];
}

// ---------------------------------------------------------------------------
// k_cf: reduce partials -> g; channel branch; FilterNorm -> cfn (B,C,9) f32.
// ---------------------------------------------------------------------------
__global__ __launch_bounds__(256) void k_cf(const float* __restrict__ partials,
                                            const float* __restrict__ cw1,
                                            const float* __restrict__ cb1,
                                            const float* __restrict__ cw2,
                                            const float* __restrict__ cb2,
                                            float* __restrict__ cfn) {
    __shared__ float g_l[B_ * C_];
    __shared__ float h1_l[B_ * MID_];
    int tid = threadIdx.x;
    g_l[tid] = (partials[tid * 3] + partials[tid * 3 + 1] + partials[tid * 3 + 2])
               * (1.0f / HW_);
    __syncthreads();
    if (tid < B_ * MID_) {
        int b = tid / MID_, m = tid % MID_;
        float acc = cb1[m];
        for (int c = 0; c < C_; ++c) acc += g_l[b * C_ + c] * cw1[m * C_ + c];
        h1_l[tid] = fmaxf(acc, 0.f);
    }
    __syncthreads();
    int b = tid >> 6, c = tid & 63;
    float f[TAPS_];
    float mean = 0.f;
    #pragma unroll
    for (int t = 0; t < TAPS_; ++t) {
        int n = c * TAPS_ + t;
        float acc = cb2[n];
        #pragma unroll
        for (int m = 0; m < MID_; ++m) acc += h1_l[b * MID_ + m] * cw2[n * MID_ + m];
        f[t] = acc;
        mean += acc;
    }
    mean *= (1.f / TAPS_);
    float var = 0.f;
    #pragma unroll
    for (int t = 0; t < TAPS_; ++t) { float d = f[t] - mean; var += d * d; }
    var *= (1.f / (TAPS_ - 1));
    float scale = STD_ / (sqrtf(fmaxf(var, 0.f)) + 1e-10f);
    #pragma unroll
    for (int t = 0; t < TAPS_; ++t)
        cfn[(b * C_ + c) * TAPS_ + t] = (f[t] - mean) * scale;
}

// ---------------------------------------------------------------------------
// k_phase: grid 2304 = (b,h) x 3 thirds of 64 px. lane = px, wave = 16 ch.
//   A: channel-split spatial filters (4 waves partial + wave-0 reduce)
//   B: DDF apply + leaky, edges via shfl; bf16 packed, swizzled rows
//   dump: coalesced copy to a_glob[b,h][s=w+4][c] (200 rows incl. zero guards)
// ---------------------------------------------------------------------------
__global__ __launch_bounds__(256, 6) void k_phase(const float* __restrict__ x,
                                                  const float* __restrict__ sw,
                                                  const float* __restrict__ sb,
                                                  const float* __restrict__ cfn,
                                                  unsigned* __restrict__ a_glob) {
    __shared__ __align__(16) char smem[13888];
    float*    pA   = (float*)smem;             // phase-A partials 4*9*64 = 9216 B
    unsigned* aT32 = (unsigned*)smem;          // phase-B out 64 rows * 36 w (alias)
    float*    s_l  = (float*)(smem + 9216);    // 9*64*4 = 2304 B
    float*    sw_l = (float*)(smem + 11520);   // 2304 B
    float*    sb_l = (float*)(smem + 13824);   // 40 B

    int bx = blockIdx.x;
    int bh = bx / 3;
    int third = bx - 3 * bh;
    int w0 = third * 64;
    int bb = bh / H_;
    int h  = bh - bb * H_;
    int tid = threadIdx.x;
    int lane = tid & 63, wid = tid >> 6;

    for (int i = tid; i < TAPS_ * C_; i += 256) sw_l[i] = sw[i];
    if (tid < TAPS_) sb_l[tid] = sb[tid];
    __syncthreads();

    // ---- Phase A: partial spatial filters (16 ch per wave) ----
    {
        float acc[TAPS_];
        #pragma unroll
        for (int t = 0; t < TAPS_; ++t) acc[t] = 0.f;
        const float* px = x + ((size_t)bb * C_ + wid * 16) * HW_ + h * W_ + w0 + lane;
        #pragma unroll
        for (int i2 = 0; i2 < 16; ++i2) {
            float xv = px[(size_t)i2 * HW_];
            #pragma unroll
            for (int t = 0; t < TAPS_; ++t)
                acc[t] = fmaf(xv, sw_l[t * C_ + wid * 16 + i2], acc[t]);
        }
        #pragma unroll
        for (int t = 0; t < TAPS_; ++t) pA[wid * 576 + t * 64 + lane] = acc[t];
    }
    __syncthreads();
    if (tid < 64) {
        float f[TAPS_];
        float mean = 0.f;
        #pragma unroll
        for (int t = 0; t < TAPS_; ++t) {
            f[t] = pA[t * 64 + tid] + pA[576 + t * 64 + tid]
                 + pA[1152 + t * 64 + tid] + pA[1728 + t * 64 + tid] + sb_l[t];
            mean += f[t];
        }
        mean *= (1.f / TAPS_);
        float var = 0.f;
        #pragma unroll
        for (int t = 0; t < TAPS_; ++t) { float d = f[t] - mean; var += d * d; }
        var *= (1.f / (TAPS_ - 1));
        float scale = STD_ / (sqrtf(fmaxf(var, 0.f)) + 1e-10f);
        #pragma unroll
        for (int t = 0; t < TAPS_; ++t) s_l[t * 64 + tid] = (f[t] - mean) * scale;
    }
    __syncthreads();   // pA region becomes aT

    // ---- Phase B: DDF apply + leaky -> aT (bf16 packed, swizzled) ----
    {
        float sreg[TAPS_];
        #pragma unroll
        for (int t = 0; t < TAPS_; ++t) sreg[t] = s_l[t * 64 + lane];
        int rok0 = (h > 0), rok2 = (h < H_ - 1);
        bool l0 = (lane == 0), l63 = (lane == 63);
        bool evalid = l0 ? (w0 > 0) : (l63 ? (w0 + 64 < W_) : false);
        int eoff = l0 ? -1 : 1;
        int key = ((lane >> 2) + 1) & 7;   // = (storage_row>>2)&7, s = w0+4+lane
        const float* xb = x + (size_t)bb * C_ * HW_ + (long)(h - 1) * W_ + w0 + lane;
        #pragma unroll 1
        for (int i = 0; i < 16; i += 2) {
            int c0 = wid * 16 + i;
            int cu = __builtin_amdgcn_readfirstlane(c0);
            const float* cfp = cfn + bb * (C_ * TAPS_) + cu * TAPS_;
            const float* p0 = xb + (size_t)c0 * HW_;
            const float* p1 = p0 + HW_;
            float acc0 = 0.f, acc1 = 0.f;
            #pragma unroll
            for (int r = 0; r < 3; ++r) {
                if (r == 0 && !rok0) continue;
                if (r == 2 && !rok2) continue;
                float v0 = p0[r * W_];
                float v1 = p1[r * W_];
                float e0 = 0.f, e1 = 0.f;
                if (evalid) { e0 = p0[r * W_ + eoff]; e1 = p1[r * W_ + eoff]; }
                float le0 = __shfl_up(v0, 1);   if (l0)  le0 = e0;
                float re0 = __shfl_down(v0, 1); if (l63) re0 = e0;
                float le1 = __shfl_up(v1, 1);   if (l0)  le1 = e1;
                float re1 = __shfl_down(v1, 1); if (l63) re1 = e1;
                int t = r * 3;
                acc0 = fmaf(le0 * sreg[t],     cfp[t],     acc0);
                acc0 = fmaf(v0  * sreg[t + 1], cfp[t + 1], acc0);
                acc0 = fmaf(re0 * sreg[t + 2], cfp[t + 2], acc0);
                acc1 = fmaf(le1 * sreg[t],     cfp[TAPS_ + t],     acc1);
                acc1 = fmaf(v1  * sreg[t + 1], cfp[TAPS_ + t + 1], acc1);
                acc1 = fmaf(re1 * sreg[t + 2], cfp[TAPS_ + t + 2], acc1);
            }
            acc0 = (acc0 >= 0.f) ? acc0 : 0.1f * acc0;
            acc1 = (acc1 >= 0.f) ? acc1 : 0.1f * acc1;
            unsigned pk = (unsigned)f2bf_bits(acc0) | ((unsigned)f2bf_bits(acc1) << 16);
            int cw = c0 >> 1;
            aT32[lane * 36 + ((((cw >> 2) ^ key) & 7) << 2) + (cw & 3)] = pk;
        }
    }
    __syncthreads();

    // ---- dump: 64 rows (+ guards) coalesced to a_glob ----
    {
        size_t gbase = (size_t)bh * 6400;
        #pragma unroll
        for (int k = 0; k < 8; ++k) {
            int idx = tid + k * 256;            // 2048 words
            int p = idx >> 5, cwp = idx & 31;
            a_glob[gbase + (size_t)(w0 + 4 + p) * 32 + cwp] = aT32[p * 36 + cwp];
        }
        if (third == 0 && tid < 128) a_glob[gbase + tid] = 0u;            // s 0..3
        if (third == 2 && tid < 128) a_glob[gbase + 6272 + tid] = 0u;     // s 196..199
    }
}

// ---------------------------------------------------------------------------
// k_gemm: grid 1536 = (b,h) x 2 halves of 96 px, 192 threads (3 waves).
//   Stage 104 rows of a_glob once (all 9 taps are row-shifts of it), then
//   mfma_f32_32x32x16: wave = n-tile(32 px), both o-tiles per wave (B-frag
//   read feeds 2 MFMAs). A-frags stream linearly from w2bf (L2-resident).
// ---------------------------------------------------------------------------
__global__ __launch_bounds__(192, 6) void k_gemm(const unsigned* __restrict__ a_glob,
                                                 const unsigned short* __restrict__ w2bf,
                                                 const float* __restrict__ bias2,
                                                 const float* __restrict__ x,
                                                 float* __restrict__ out) {
    __shared__ __align__(16) unsigned Bbuf[104 * 36];   // 14976 B
    __shared__ float b2_l[64];
    const short* BbufS = (const short*)Bbuf;

    int bx = blockIdx.x;
    int bh = bx >> 1;
    int half = bx & 1;
    int w0 = half * 96;
    int bb = bh / H_;
    int h  = bh - bb * H_;
    int tid = threadIdx.x;
    int lane = tid & 63, wid = tid >> 6;     // wid = n-tile 0..2
    int l32 = lane & 31, khalf = lane >> 5;

    // ---- stage 104 rows x 32 words, coalesced -> stride-36 LDS rows ----
    {
        const unsigned* gsrc = a_glob + (size_t)bh * 6400 + (size_t)w0 * 32;
        #pragma unroll 2
        for (int i = tid; i < 3328; i += 192)
            Bbuf[(i >> 5) * 36 + (i & 31)] = gsrc[i];
        if (tid < 64) b2_l[tid] = bias2[tid];
    }
    __syncthreads();

    // ---- MFMA loop: 36 steps = 9 taps x 4 K16-groups ----
    {
        f32x16 acc0, acc1;
        #pragma unroll
        for (int i = 0; i < 16; ++i) { acc0[i] = 0.f; acc1[i] = 0.f; }

        const short* arow0 = (const short*)w2bf + (size_t)l32 * K_TOT + khalf * 8;
        const short* arow1 = arow0 + 32 * K_TOT;
        short8 A0c = *(const short8*)(arow0);
        short8 A1c = *(const short8*)(arow1);

        #pragma unroll 4
        for (int step = 0; step < 36; ++step) {
            short8 A0n = A0c, A1n = A1c;
            if (step < 35) {
                A0n = *(const short8*)(arow0 + (step + 1) * 16);
                A1n = *(const short8*)(arow1 + (step + 1) * 16);
            }
            int t = step >> 2, kk = step & 3;
            int ch = (kk << 1) + khalf;                 // 16-B chunk 0..7
            int L = t + wid * 32 + l32;                 // local row, storage s=w0+L
            int key = (L >> 2) & 7;                     // w0>>2 === 0 (mod 8)
            int off = L * AT_STRIDE + (((ch ^ key) & 7) << 3);
            short8 bf = *(const short8*)(BbufS + off);
            acc0 = __builtin_amdgcn_mfma_f32_32x32x16_bf16(A0c, bf, acc0, 0, 0, 0);
            acc1 = __builtin_amdgcn_mfma_f32_32x32x16_bf16(A1c, bf, acc1, 0, 0, 0);
            A0c = A0n; A1c = A1n;
        }

        // epilogue: C/D col=l32, row=(reg&3)+8*(reg>>2)+4*khalf  [m74/m101]
        size_t xbase = (size_t)bb * C_ * HW_ + (size_t)h * W_;
        int w = w0 + wid * 32 + l32;
        #pragma unroll
        for (int reg = 0; reg < 16; ++reg) {
            int om = (reg & 3) + ((reg >> 2) << 3) + (khalf << 2);
            size_t i0 = xbase + (size_t)om * HW_ + w;
            size_t i1 = xbase + (size_t)(om + 32) * HW_ + w;
            out[i0] = acc0[reg] + b2_l[om] + x[i0];
            out[i1] = acc1[reg] + b2_l[om + 32] + x[i1];
        }
    }
}

// ---------------------------------------------------------------------------
// Fallback (round-7 fused kernel) if workspace can't hold a_glob.
// ---------------------------------------------------------------------------
__global__ __launch_bounds__(256, 3) void k_main_fused(const float* __restrict__ x,
                                                       const float* __restrict__ sw,
                                                       const float* __restrict__ sb,
                                                       const float* __restrict__ cfn,
                                                       const unsigned short* __restrict__ w2bf,
                                                       const float* __restrict__ bias2,
                                                       float* __restrict__ out) {
    __shared__ __align__(16) char smem[36016];
    short*          aT   = (short*)smem;
    unsigned*       aT32 = (unsigned*)smem;
    float*          sw_l = (float*)smem;
    float*          s_l  = (float*)(smem + 28800);
    float*          b2_l = (float*)(smem + 35712);
    float*          sb_l = (float*)(smem + 35968);

    int bh = blockIdx.x;
    int bb = bh / H_;
    int h  = bh - bb * H_;
    int tid = threadIdx.x;
    int lane = tid & 63, wid = tid >> 6;
    int quad = lane >> 4, l16 = lane & 15;
    int obase = wid * 16;

    for (int i = tid; i < TAPS_ * C_; i += 256) sw_l[i] = sw[i];
    if (tid < C_) b2_l[tid] = bias2[tid];
    if (tid < TAPS_) sb_l[tid] = sb[tid];
    __syncthreads();

    const short* w2s = (const short*)w2bf;
    const short* arow = w2s + (obase + l16) * K_TOT + quad * 8;
    short8 a0 = *(const short8*)(arow);
    short8 a1 = *(const short8*)(arow + 32);

    if (tid < W_) {
        int w = tid;
        float acc[TAPS_];
        #pragma unroll
        for (int t = 0; t < TAPS_; ++t) acc[t] = sb_l[t];
        const float* px = x + (size_t)bb * C_ * HW_ + h * W_ + w;
        #pragma unroll 8
        for (int c = 0; c < C_; ++c) {
            float xv = px[(size_t)c * HW_];
            #pragma unroll
            for (int t = 0; t < TAPS_; ++t) acc[t] = fmaf(xv, sw_l[t * C_ + c], acc[t]);
        }
        float mean = 0.f;
        #pragma unroll
        for (int t = 0; t < TAPS_; ++t) mean += acc[t];
        mean *= (1.f / TAPS_);
        float var = 0.f;
        #pragma unroll
        for (int t = 0; t < TAPS_; ++t) { float d = acc[t] - mean; var += d * d; }
        var *= (1.f / (TAPS_ - 1));
        float scale = STD_ / (sqrtf(fmaxf(var, 0.f)) + 1e-10f);
        float* sp = s_l + (w & 3) * 432 + (w >> 2);
        #pragma unroll
        for (int t = 0; t < TAPS_; ++t) sp[t * 48] = (acc[t] - mean) * scale;
    }
    __syncthreads();

    for (int i = tid; i < 8 * (AT_STRIDE / 2); i += 256) {
        int rowIdx = i / (AT_STRIDE / 2);
        int col    = i - rowIdx * (AT_STRIDE / 2);
        int r = (rowIdx < 4) ? rowIdx : (192 + rowIdx);
        aT32[r * (AT_STRIDE / 2) + col] = 0u;
    }

    {
        int wbase = wid * 16;
        if (lane < 48) {
            int w0 = 4 * lane;
            float sreg[4][TAPS_];
            #pragma unroll
            for (int k = 0; k < 4; ++k) {
                const float* sp = s_l + k * 432 + lane;
                #pragma unroll
                for (int t = 0; t < TAPS_; ++t) sreg[k][t] = sp[t * 48];
            }
            bool l0 = (lane == 0), l47 = (lane == 47);
            int rok0 = (h > 0), rok2 = (h < H_ - 1);
            int midx = l0 ? 0 : (w0 - 1);
            int pidx = l47 ? w0 : (w0 + 4);
            const float* xbase = x + (long)bb * C_ * HW_ + (long)(h - 1) * W_;
            #pragma unroll 1
            for (int i = 0; i < 16; i += 2) {
                int c0 = wbase + i;
                int cu = __builtin_amdgcn_readfirstlane(c0);
                const float* cfp = cfn + bb * (C_ * TAPS_) + cu * TAPS_;
                const float* pc0 = xbase + (long)c0 * HW_;
                const float* pc1 = pc0 + HW_;
                float acc0[4] = {0.f, 0.f, 0.f, 0.f};
                float acc1[4] = {0.f, 0.f, 0.f, 0.f};
                #pragma unroll
                for (int r = 0; r < 3; ++r) {
                    if (r == 0 && !rok0) continue;
                    if (r == 2 && !rok2) continue;
                    const float* p0 = pc0 + r * W_;
                    const float* p1 = pc1 + r * W_;
                    float4 fa = *(const float4*)(p0 + w0);
                    float4 fb = *(const float4*)(p1 + w0);
                    float ma = l0 ? 0.f : p0[midx];
                    float mb = l0 ? 0.f : p1[midx];
                    float pa = l47 ? 0.f : p0[pidx];
                    float pb = l47 ? 0.f : p1[pidx];
                    float va[6] = { ma, fa.x, fa.y, fa.z, fa.w, pa };
                    float vb[6] = { mb, fb.x, fb.y, fb.z, fb.w, pb };
                    #pragma unroll
                    for (int dc = 0; dc < 3; ++dc) {
                        int t = r * 3 + dc;
                        float cva = cfp[t];
                        float cvb = cfp[TAPS_ + t];
                        #pragma unroll
                        for (int k = 0; k < 4; ++k) {
                            acc0[k] = fmaf(va[k + dc] * sreg[k][t], cva, acc0[k]);
                            acc1[k] = fmaf(vb[k + dc] * sreg[k][t], cvb, acc1[k]);
                        }
                    }
                }
                int cw = c0 >> 1;
                #pragma unroll
                for (int k = 0; k < 4; ++k) {
                    float a0v = acc0[k]; a0v = (a0v >= 0.f) ? a0v : 0.1f * a0v;
                    float a1v = acc1[k]; a1v = (a1v >= 0.f) ? a1v : 0.1f * a1v;
                    unsigned pk = (unsigned)f2bf_bits(a0v)
                                | ((unsigned)f2bf_bits(a1v) << 16);
                    aT32[at_word(w0 + k + 4, cw)] = pk;
                }
            }
        }
    }
    __syncthreads();

    {
        f32x4 acc[12];
        #pragma unroll
        for (int n = 0; n < 12; ++n) acc[n] = (f32x4){0.f, 0.f, 0.f, 0.f};

        #pragma unroll 1
        for (int kk = 0; kk < 18; ++kk) {
            short8 a2 = a1;
            if (kk < 16) a2 = *(const short8*)(arow + (kk + 2) * 32);
            int t = kk >> 1;
            int ch = ((kk & 1) << 2) + quad;
            int rowb = l16 + t;
            int key0 = (rowb >> 2) & 7;
            int off0 = rowb * AT_STRIDE + (((ch ^ key0) & 7) << 3);
            int off1 = rowb * AT_STRIDE + (((ch ^ key0 ^ 4) & 7) << 3);
            #pragma unroll
            for (int n = 0; n < 12; ++n) {
                int off = ((n & 1) ? off1 : off0) + n * 16 * AT_STRIDE;
                short8 bf = *(const short8*)(aT + off);
                acc[n] = __builtin_amdgcn_mfma_f32_16x16x32_bf16(a0, bf, acc[n], 0, 0, 0);
            }
            a0 = a1; a1 = a2;
        }

        size_t xbase = (size_t)bb * C_ * HW_ + (size_t)h * W_;
        #pragma unroll
        for (int n = 0; n < 12; ++n) {
            int w = n * 16 + l16;
            #pragma unroll
            for (int reg = 0; reg < 4; ++reg) {
                int o = obase + quad * 4 + reg;
                size_t idx = xbase + (size_t)o * HW_ + w;
                out[idx] = acc[n][reg] + b2_l[o] + x[idx];
            }
        }
    }
}

// ---------------------------------------------------------------------------
extern "C" void kernel_launch(void* const* d_in, const int* in_sizes, int n_in,
                              void* d_out, int out_size, void* d_ws, size_t ws_size,
                              hipStream_t stream) {
    const float* x   = (const float*)d_in[0];
    const float* sw  = (const float*)d_in[1];
    const float* sb  = (const float*)d_in[2];
    const float* cw1 = (const float*)d_in[3];
    const float* cb1 = (const float*)d_in[4];
    const float* cw2 = (const float*)d_in[5];
    const float* cb2 = (const float*)d_in[6];
    const float* w2  = (const float*)d_in[7];
    const float* b2  = (const float*)d_in[8];
    float* out = (float*)d_out;

    unsigned short* w2bf = (unsigned short*)d_ws;                 // 73728 B
    float* partials = (float*)((char*)d_ws + 73728);              // 3072 B
    float* cfn      = (float*)((char*)d_ws + 76800);              // 9216 B
    unsigned* a_glob = (unsigned*)((char*)d_ws + 90112);          // 19660800 B

    hipLaunchKernelGGL(k_pre, dim3(912), dim3(256), 0, stream, x, w2, w2bf, partials);
    hipLaunchKernelGGL(k_cf, dim3(1), dim3(256), 0, stream,
                       partials, cw1, cb1, cw2, cb2, cfn);
    if (ws_size >= 19750912ull) {
        hipLaunchKernelGGL(k_phase, dim3(B_ * H_ * 3), dim3(256), 0, stream,
                           x, sw, sb, cfn, a_glob);
        hipLaunchKernelGGL(k_gemm, dim3(B_ * H_ * 2), dim3(192), 0, stream,
                           a_glob, w2bf, b2, x, out);
    } else {
        hipLaunchKernelGGL(k_main_fused, dim3(B_ * H_), dim3(256), 0, stream,
                           x, sw, sb, cfn, w2bf, b2, out);
    }
}

// Round 11
// 165.533 us; speedup vs baseline: 1.1640x; 1.1640x over previous
//
#include <hip/hip_runtime.h>
#include <hip/hip_bf16.h>

#define B_    4
#define C_    64
#define H_    192
#define W_    192
#define TAPS_ 9
#define MID_  12
#define HW_   (H_ * W_)
#define K_TOT 576                      // C_ * TAPS_
#define AT_STRIDE 72                   // bf16 elems per Bbuf row (8 chunks + pad)

constexpr float STD_ = 0.47140452079103173f;  // sqrt(2)/3

using bf16 = __hip_bfloat16;
typedef __attribute__((ext_vector_type(16))) float f32x16;
typedef __attribute__((ext_vector_type(8)))  short short8;

__device__ __forceinline__ unsigned short f2bf_bits(float v) {
    union { bf16 h; unsigned short u; } cv;
    cv.h = __float2bfloat16(v);   // RNE
    return cv.u;
}

// ---------------------------------------------------------------------------
// k_pre: {w2 repack -> bf16 FRAGMENT-MAJOR w2frag[step][otile][lane][8]}
//        (blocks 0..143) and {x row partial sums} (blocks 144..911).
// Fragment layout (mfma_f32_32x32x16_bf16, HW-validated rounds 9/10):
//   A[m = lane&31][k = (lane>>5)*8 + j]; GEMM K-index q = t*64 + c with
//   t = step>>2, c = (step&3)*16 + (lane>>5)*8 + j.
// ---------------------------------------------------------------------------
__global__ __launch_bounds__(256) void k_pre(const float* __restrict__ x,
                                             const float* __restrict__ w2,
                                             unsigned short* __restrict__ w2frag,
                                             float* __restrict__ partials) {
    int bx = blockIdx.x;
    if (bx < 144) {
        int s = bx * 256 + threadIdx.x;      // source index (coalesced read)
        int o = s / K_TOT;
        int rem = s - o * K_TOT;
        int c = rem / TAPS_;
        int t = rem - c * TAPS_;
        int step  = (t << 2) + (c >> 4);     // 0..35
        int khalf = (c >> 3) & 1;
        int j     = c & 7;
        int lane2 = khalf * 32 + (o & 31);
        int otile = o >> 5;
        w2frag[((step * 2 + otile) * 64 + lane2) * 8 + j] = f2bf_bits(w2[s]);
        return;
    }
    bx -= 144;
    int bc = bx / 3, part = bx - 3 * (bx / 3);
    const float4* p = (const float4*)(x + (size_t)bc * HW_ + part * 12288);
    float s = 0.f;
    #pragma unroll
    for (int k = 0; k < 12; ++k) {
        float4 u = p[threadIdx.x + k * 256];
        s += u.x + u.y + u.z + u.w;
    }
    #pragma unroll
    for (int off = 32; off; off >>= 1) s += __shfl_down(s, off);
    __shared__ float red[4];
    if ((threadIdx.x & 63) == 0) red[threadIdx.x >> 6] = s;
    __syncthreads();
    if (threadIdx.x == 0)
        partials[bx] = red[0] + red[1] + red[2] + red[3];
}

// ---------------------------------------------------------------------------
// k_cf: reduce partials -> g; channel branch; FilterNorm -> cfn (B,C,9) f32.
// ---------------------------------------------------------------------------
__global__ __launch_bounds__(256) void k_cf(const float* __restrict__ partials,
                                            const float* __restrict__ cw1,
                                            const float* __restrict__ cb1,
                                            const float* __restrict__ cw2,
                                            const float* __restrict__ cb2,
                                            float* __restrict__ cfn) {
    __shared__ float g_l[B_ * C_];
    __shared__ float h1_l[B_ * MID_];
    int tid = threadIdx.x;
    g_l[tid] = (partials[tid * 3] + partials[tid * 3 + 1] + partials[tid * 3 + 2])
               * (1.0f / HW_);
    __syncthreads();
    if (tid < B_ * MID_) {
        int b = tid / MID_, m = tid % MID_;
        float acc = cb1[m];
        for (int c = 0; c < C_; ++c) acc += g_l[b * C_ + c] * cw1[m * C_ + c];
        h1_l[tid] = fmaxf(acc, 0.f);
    }
    __syncthreads();
    int b = tid >> 6, c = tid & 63;
    float f[TAPS_];
    float mean = 0.f;
    #pragma unroll
    for (int t = 0; t < TAPS_; ++t) {
        int n = c * TAPS_ + t;
        float acc = cb2[n];
        #pragma unroll
        for (int m = 0; m < MID_; ++m) acc += h1_l[b * MID_ + m] * cw2[n * MID_ + m];
        f[t] = acc;
        mean += acc;
    }
    mean *= (1.f / TAPS_);
    float var = 0.f;
    #pragma unroll
    for (int t = 0; t < TAPS_; ++t) { float d = f[t] - mean; var += d * d; }
    var *= (1.f / (TAPS_ - 1));
    float scale = STD_ / (sqrtf(fmaxf(var, 0.f)) + 1e-10f);
    #pragma unroll
    for (int t = 0; t < TAPS_; ++t)
        cfn[(b * C_ + c) * TAPS_ + t] = (f[t] - mean) * scale;
}

// ---------------------------------------------------------------------------
// k_phase: grid 2304 = (b,h) x 3 thirds of 64 px. lane = px, wave = 16 ch.
//   A: channel-split spatial filters (4 waves partial + wave-0 reduce)
//   B: DDF apply + leaky, edges via shfl; bf16 packed, swizzled rows
//   dump: coalesced copy to a_glob[b,h][s=w+4][c] (200 rows incl. zero guards)
// ---------------------------------------------------------------------------
__global__ __launch_bounds__(256, 6) void k_phase(const float* __restrict__ x,
                                                  const float* __restrict__ sw,
                                                  const float* __restrict__ sb,
                                                  const float* __restrict__ cfn,
                                                  unsigned* __restrict__ a_glob) {
    __shared__ __align__(16) char smem[13888];
    float*    pA   = (float*)smem;             // phase-A partials 4*9*64 = 9216 B
    unsigned* aT32 = (unsigned*)smem;          // phase-B out 64 rows * 36 w (alias)
    float*    s_l  = (float*)(smem + 9216);    // 9*64*4 = 2304 B
    float*    sw_l = (float*)(smem + 11520);   // 2304 B
    float*    sb_l = (float*)(smem + 13824);   // 40 B

    int bx = blockIdx.x;
    int bh = bx / 3;
    int third = bx - 3 * bh;
    int w0 = third * 64;
    int bb = bh / H_;
    int h  = bh - bb * H_;
    int tid = threadIdx.x;
    int lane = tid & 63, wid = tid >> 6;

    for (int i = tid; i < TAPS_ * C_; i += 256) sw_l[i] = sw[i];
    if (tid < TAPS_) sb_l[tid] = sb[tid];
    __syncthreads();

    // ---- Phase A: partial spatial filters (16 ch per wave) ----
    {
        float acc[TAPS_];
        #pragma unroll
        for (int t = 0; t < TAPS_; ++t) acc[t] = 0.f;
        const float* px = x + ((size_t)bb * C_ + wid * 16) * HW_ + h * W_ + w0 + lane;
        #pragma unroll
        for (int i2 = 0; i2 < 16; ++i2) {
            float xv = px[(size_t)i2 * HW_];
            #pragma unroll
            for (int t = 0; t < TAPS_; ++t)
                acc[t] = fmaf(xv, sw_l[t * C_ + wid * 16 + i2], acc[t]);
        }
        #pragma unroll
        for (int t = 0; t < TAPS_; ++t) pA[wid * 576 + t * 64 + lane] = acc[t];
    }
    __syncthreads();
    if (tid < 64) {
        float f[TAPS_];
        float mean = 0.f;
        #pragma unroll
        for (int t = 0; t < TAPS_; ++t) {
            f[t] = pA[t * 64 + tid] + pA[576 + t * 64 + tid]
                 + pA[1152 + t * 64 + tid] + pA[1728 + t * 64 + tid] + sb_l[t];
            mean += f[t];
        }
        mean *= (1.f / TAPS_);
        float var = 0.f;
        #pragma unroll
        for (int t = 0; t < TAPS_; ++t) { float d = f[t] - mean; var += d * d; }
        var *= (1.f / (TAPS_ - 1));
        float scale = STD_ / (sqrtf(fmaxf(var, 0.f)) + 1e-10f);
        #pragma unroll
        for (int t = 0; t < TAPS_; ++t) s_l[t * 64 + tid] = (f[t] - mean) * scale;
    }
    __syncthreads();   // pA region becomes aT

    // ---- Phase B: DDF apply + leaky -> aT (bf16 packed, swizzled) ----
    {
        float sreg[TAPS_];
        #pragma unroll
        for (int t = 0; t < TAPS_; ++t) sreg[t] = s_l[t * 64 + lane];
        int rok0 = (h > 0), rok2 = (h < H_ - 1);
        bool l0 = (lane == 0), l63 = (lane == 63);
        bool evalid = l0 ? (w0 > 0) : (l63 ? (w0 + 64 < W_) : false);
        int eoff = l0 ? -1 : 1;
        int key = ((lane >> 2) + 1) & 7;   // = (storage_row>>2)&7, s = w0+4+lane
        const float* xb = x + (size_t)bb * C_ * HW_ + (long)(h - 1) * W_ + w0 + lane;
        #pragma unroll 2
        for (int i = 0; i < 16; i += 2) {
            int c0 = wid * 16 + i;
            int cu = __builtin_amdgcn_readfirstlane(c0);
            const float* cfp = cfn + bb * (C_ * TAPS_) + cu * TAPS_;
            const float* p0 = xb + (size_t)c0 * HW_;
            const float* p1 = p0 + HW_;
            float acc0 = 0.f, acc1 = 0.f;
            #pragma unroll
            for (int r = 0; r < 3; ++r) {
                if (r == 0 && !rok0) continue;
                if (r == 2 && !rok2) continue;
                float v0 = p0[r * W_];
                float v1 = p1[r * W_];
                float e0 = 0.f, e1 = 0.f;
                if (evalid) { e0 = p0[r * W_ + eoff]; e1 = p1[r * W_ + eoff]; }
                float le0 = __shfl_up(v0, 1);   if (l0)  le0 = e0;
                float re0 = __shfl_down(v0, 1); if (l63) re0 = e0;
                float le1 = __shfl_up(v1, 1);   if (l0)  le1 = e1;
                float re1 = __shfl_down(v1, 1); if (l63) re1 = e1;
                int t = r * 3;
                acc0 = fmaf(le0 * sreg[t],     cfp[t],     acc0);
                acc0 = fmaf(v0  * sreg[t + 1], cfp[t + 1], acc0);
                acc0 = fmaf(re0 * sreg[t + 2], cfp[t + 2], acc0);
                acc1 = fmaf(le1 * sreg[t],     cfp[TAPS_ + t],     acc1);
                acc1 = fmaf(v1  * sreg[t + 1], cfp[TAPS_ + t + 1], acc1);
                acc1 = fmaf(re1 * sreg[t + 2], cfp[TAPS_ + t + 2], acc1);
            }
            acc0 = (acc0 >= 0.f) ? acc0 : 0.1f * acc0;
            acc1 = (acc1 >= 0.f) ? acc1 : 0.1f * acc1;
            unsigned pk = (unsigned)f2bf_bits(acc0) | ((unsigned)f2bf_bits(acc1) << 16);
            int cw = c0 >> 1;
            aT32[lane * 36 + ((((cw >> 2) ^ key) & 7) << 2) + (cw & 3)] = pk;
        }
    }
    __syncthreads();

    // ---- dump: 64 rows (+ guards) coalesced to a_glob ----
    {
        size_t gbase = (size_t)bh * 6400;
        #pragma unroll
        for (int k = 0; k < 8; ++k) {
            int idx = tid + k * 256;            // 2048 words
            int p = idx >> 5, cwp = idx & 31;
            a_glob[gbase + (size_t)(w0 + 4 + p) * 32 + cwp] = aT32[p * 36 + cwp];
        }
        if (third == 0 && tid < 128) a_glob[gbase + tid] = 0u;            // s 0..3
        if (third == 2 && tid < 128) a_glob[gbase + 6272 + tid] = 0u;     // s 196..199
    }
}

// ---------------------------------------------------------------------------
// k_gemm: grid 1536 = (b,h) x 2 halves of 96 px, 192 threads (3 waves).
//   Stage 104 rows of a_glob once (all 9 taps are row-shifts of it), then
//   mfma_f32_32x32x16: wave = n-tile(32 px), both o-tiles per wave.
//   A-frags from FRAGMENT-MAJOR w2frag: each wave-load = 1 KB contiguous
//   (8 cache lines, was 64); dist-2 rolling window; preloads issued before
//   staging so L2 latency overlaps the barrier.
// ---------------------------------------------------------------------------
__global__ __launch_bounds__(192, 6) void k_gemm(const unsigned* __restrict__ a_glob,
                                                 const unsigned short* __restrict__ w2frag,
                                                 const float* __restrict__ bias2,
                                                 const float* __restrict__ x,
                                                 float* __restrict__ out) {
    __shared__ __align__(16) unsigned Bbuf[104 * 36];   // 14976 B
    __shared__ float b2_l[64];
    const short* BbufS = (const short*)Bbuf;

    int bx = blockIdx.x;
    int bh = bx >> 1;
    int half = bx & 1;
    int w0 = half * 96;
    int bb = bh / H_;
    int h  = bh - bb * H_;
    int tid = threadIdx.x;
    int lane = tid & 63, wid = tid >> 6;     // wid = n-tile 0..2
    int l32 = lane & 31, khalf = lane >> 5;

    // ---- A-frag preloads (before staging: latency overlaps barrier) ----
    const short* af = (const short*)w2frag + lane * 8;   // + step*1024 (+512 o-tile 1)
    short8 A0c = *(const short8*)(af);
    short8 A1c = *(const short8*)(af + 512);
    short8 A0n = *(const short8*)(af + 1024);
    short8 A1n = *(const short8*)(af + 1536);

    // ---- stage 104 rows x 32 words, coalesced -> stride-36 LDS rows ----
    {
        const unsigned* gsrc = a_glob + (size_t)bh * 6400 + (size_t)w0 * 32;
        #pragma unroll 2
        for (int i = tid; i < 3328; i += 192)
            Bbuf[(i >> 5) * 36 + (i & 31)] = gsrc[i];
        if (tid < 64) b2_l[tid] = bias2[tid];
    }
    __syncthreads();

    // ---- MFMA loop: 36 steps = 9 taps x 4 K16-groups ----
    {
        f32x16 acc0, acc1;
        #pragma unroll
        for (int i = 0; i < 16; ++i) { acc0[i] = 0.f; acc1[i] = 0.f; }

        #pragma unroll 4
        for (int step = 0; step < 36; ++step) {
            short8 A0nn = A0c, A1nn = A1c;
            if (step < 34) {
                A0nn = *(const short8*)(af + (step + 2) * 1024);
                A1nn = *(const short8*)(af + (step + 2) * 1024 + 512);
            }
            int t = step >> 2, kk = step & 3;
            int ch = (kk << 1) + khalf;                 // 16-B chunk 0..7
            int L = t + wid * 32 + l32;                 // local row, storage s=w0+L
            int key = (L >> 2) & 7;                     // w0>>2 === 0 (mod 8)
            int off = L * AT_STRIDE + (((ch ^ key) & 7) << 3);
            short8 bf = *(const short8*)(BbufS + off);
            acc0 = __builtin_amdgcn_mfma_f32_32x32x16_bf16(A0c, bf, acc0, 0, 0, 0);
            acc1 = __builtin_amdgcn_mfma_f32_32x32x16_bf16(A1c, bf, acc1, 0, 0, 0);
            A0c = A0n; A0n = A0nn;
            A1c = A1n; A1n = A1nn;
        }

        // epilogue: C/D col=l32, row=(reg&3)+8*(reg>>2)+4*khalf  [m74/m101]
        size_t xbase = (size_t)bb * C_ * HW_ + (size_t)h * W_;
        int w = w0 + wid * 32 + l32;
        #pragma unroll
        for (int reg = 0; reg < 16; ++reg) {
            int om = (reg & 3) + ((reg >> 2) << 3) + (khalf << 2);
            size_t i0 = xbase + (size_t)om * HW_ + w;
            size_t i1 = xbase + (size_t)(om + 32) * HW_ + w;
            out[i0] = acc0[reg] + b2_l[om] + x[i0];
            out[i1] = acc1[reg] + b2_l[om + 32] + x[i1];
        }
    }
}

// ---------------------------------------------------------------------------
extern "C" void kernel_launch(void* const* d_in, const int* in_sizes, int n_in,
                              void* d_out, int out_size, void* d_ws, size_t ws_size,
                              hipStream_t stream) {
    const float* x   = (const float*)d_in[0];
    const float* sw  = (const float*)d_in[1];
    const float* sb  = (const float*)d_in[2];
    const float* cw1 = (const float*)d_in[3];
    const float* cb1 = (const float*)d_in[4];
    const float* cw2 = (const float*)d_in[5];
    const float* cb2 = (const float*)d_in[6];
    const float* w2  = (const float*)d_in[7];
    const float* b2  = (const float*)d_in[8];
    float* out = (float*)d_out;

    unsigned short* w2frag = (unsigned short*)d_ws;               // 73728 B
    float* partials = (float*)((char*)d_ws + 73728);              // 3072 B
    float* cfn      = (float*)((char*)d_ws + 76800);              // 9216 B
    unsigned* a_glob = (unsigned*)((char*)d_ws + 90112);          // 19660800 B

    hipLaunchKernelGGL(k_pre, dim3(912), dim3(256), 0, stream, x, w2, w2frag, partials);
    hipLaunchKernelGGL(k_cf, dim3(1), dim3(256), 0, stream,
                       partials, cw1, cb1, cw2, cb2, cfn);
    hipLaunchKernelGGL(k_phase, dim3(B_ * H_ * 3), dim3(256), 0, stream,
                       x, sw, sb, cfn, a_glob);
    hipLaunchKernelGGL(k_gemm, dim3(B_ * H_ * 2), dim3(192), 0, stream,
                       a_glob, w2frag, b2, x, out);
}